// Round 7
// baseline (185.251 us; speedup 1.0000x reference)
//
#include <hip/hip_runtime.h>

#define HH 2048
#define NPIX (HH * HH)      // 4194304
#define NBINS 256
#define NRBINS 512          // refined bins: r = hb + tb, r in [0,510]
#define NQ (NPIX / 4)       // 1048576 float4 quads

#define BLOCKS 512
#define THREADS 512
#define ITERS (NQ / (BLOCKS * THREADS))   // 4 exactly

#define CNT_SHIFT 42
#define FRAC_MASK ((1ULL << CNT_SHIFT) - 1)

// Accumulator word layout (all u64):
//   [0, 1536)      : refined src stats per channel (count<<42 | frac fixpt sum)
//   [1536, 2304)   : tar masked hist counts per channel
#define NWORDS (3 * NRBINS + 3 * NBINS)   // 2304
#define NSPLIT 32                         // split copies to kill atomic contention
// workspace: u64 part[NSPLIT][NWORDS] then u64 gfin[NWORDS]
#define PART_BYTES ((size_t)NSPLIT * NWORDS * 8)
#define WS_ZERO_BYTES (PART_BYTES + (size_t)NWORDS * 8)

__device__ __forceinline__ float denorm255(float x) {
    // matches clip((x+1)*0.5, 0, 1) * 255 in fp32
    return fminf(fmaxf((x + 1.0f) * 0.5f, 0.0f), 1.0f) * 255.0f;
}

__global__ __launch_bounds__(THREADS, 8) void fused_hist(
        const float* __restrict__ in, const float* __restrict__ tarp,
        const float* __restrict__ ms, const float* __restrict__ mt,
        unsigned long long* __restrict__ part) {
    __shared__ unsigned long long lpk[3 * NRBINS];  // 12 KB
    __shared__ unsigned lht[3 * NBINS];             // 3 KB
    for (int i = threadIdx.x; i < 3 * NRBINS; i += THREADS) lpk[i] = 0ULL;
    for (int i = threadIdx.x; i < 3 * NBINS; i += THREADS) lht[i] = 0u;
    __syncthreads();

    const float BSCALE = 256.0f / 255.0f;  // same nearest-f32 constant as jnp
    const float FSCALE = 4194304.0f;       // 2^22
    const int stride = BLOCKS * THREADS;
    int idx = blockIdx.x * THREADS + threadIdx.x;

    // software pipeline: load iteration s+1 while binning iteration s
    float4 cm  = ((const float4*)ms)[idx];
    float4 ct  = ((const float4*)mt)[idx];
    float4 ca0 = ((const float4*)(in))[idx];
    float4 ca1 = ((const float4*)(in + NPIX))[idx];
    float4 ca2 = ((const float4*)(in + 2 * NPIX))[idx];
    float4 cb0 = ((const float4*)(tarp))[idx];
    float4 cb1 = ((const float4*)(tarp + NPIX))[idx];
    float4 cb2 = ((const float4*)(tarp + 2 * NPIX))[idx];

    #pragma unroll
    for (int s = 0; s < ITERS; ++s) {
        float4 nm, nt4, na0, na1, na2, nb0, nb1, nb2;
        const int nidx = idx + stride;
        if (s < ITERS - 1) {
            nm  = ((const float4*)ms)[nidx];
            nt4 = ((const float4*)mt)[nidx];
            na0 = ((const float4*)(in))[nidx];
            na1 = ((const float4*)(in + NPIX))[nidx];
            na2 = ((const float4*)(in + 2 * NPIX))[nidx];
            nb0 = ((const float4*)(tarp))[nidx];
            nb1 = ((const float4*)(tarp + NPIX))[nidx];
            nb2 = ((const float4*)(tarp + 2 * NPIX))[nidx];
        }

        const float mv[4] = {cm.x, cm.y, cm.z, cm.w};
        const float tv[4] = {ct.x, ct.y, ct.z, ct.w};
        const float av[3][4] = {{ca0.x, ca0.y, ca0.z, ca0.w},
                                {ca1.x, ca1.y, ca1.z, ca1.w},
                                {ca2.x, ca2.y, ca2.z, ca2.w}};
        const float bv[3][4] = {{cb0.x, cb0.y, cb0.z, cb0.w},
                                {cb1.x, cb1.y, cb1.z, cb1.w},
                                {cb2.x, cb2.y, cb2.z, cb2.w}};

        #pragma unroll
        for (int ch = 0; ch < 3; ++ch) {
            #pragma unroll
            for (int k = 0; k < 4; ++k) {
                if (mv[k] != 0.0f) {
                    // src pixel: one u64 atomic carries hist count + trunc frac
                    float v = denorm255(av[ch][k]);
                    int hb = min((int)(v * BSCALE), NBINS - 1);  // floor, v>=0
                    int tb = (int)v;                             // [0,255]
                    // v - tb Sterbenz-exact; *2^22 exact; trunc err < 2^-22
                    unsigned fr = (unsigned)((v - (float)tb) * FSCALE);
                    atomicAdd(&lpk[ch * NRBINS + hb + tb],
                              (1ULL << CNT_SHIFT) | (unsigned long long)fr);
                }
                if (tv[k] != 0.0f) {
                    float w = denorm255(bv[ch][k]);
                    int wb = min((int)(w * BSCALE), NBINS - 1);
                    atomicAdd(&lht[ch * NBINS + wb], 1u);
                }
            }
        }
        if (s < ITERS - 1) {
            cm = nm; ct = nt4;
            ca0 = na0; ca1 = na1; ca2 = na2;
            cb0 = nb0; cb1 = nb1; cb2 = nb2;
        }
        idx = nidx;
    }
    __syncthreads();

    // flush into this block's split copy: contention per word = BLOCKS/NSPLIT = 16
    unsigned long long* my = part + (size_t)(blockIdx.x % NSPLIT) * NWORDS;
    for (int i = threadIdx.x; i < 3 * NRBINS; i += THREADS) {
        unsigned long long p = lpk[i];
        if (p) atomicAdd(&my[i], p);
    }
    for (int i = threadIdx.x; i < 3 * NBINS; i += THREADS) {
        unsigned h = lht[i];
        if (h) atomicAdd(&my[3 * NRBINS + i], (unsigned long long)h);
    }
}

__global__ __launch_bounds__(256) void reduce_kernel(
        const unsigned long long* __restrict__ part,
        unsigned long long* __restrict__ gfin) {
    const int w = blockIdx.x * 256 + threadIdx.x;  // [0, NWORDS)
    unsigned long long s = 0ULL;
    #pragma unroll
    for (int c = 0; c < NSPLIT; ++c) s += part[(size_t)c * NWORDS + w];
    gfin[w] = s;
}

__global__ __launch_bounds__(NBINS) void table_loss(
        const unsigned long long* __restrict__ gfin, float* __restrict__ out) {
    __shared__ float cdf[6][NBINS];
    __shared__ float tot[6];
    const int t = threadIdx.x;  // 0..255

    // decode refined bins: hist bin t gets counts from r=2t and r=2t-1
    unsigned long long pe[3], po[3];
    #pragma unroll
    for (int ch = 0; ch < 3; ++ch) {
        pe[ch] = gfin[ch * NRBINS + 2 * t];
        po[ch] = gfin[ch * NRBINS + 2 * t + 1];
        unsigned long long pp = (t > 0) ? gfin[ch * NRBINS + 2 * t - 1] : 0ULL;
        cdf[ch][t] = (float)((pe[ch] >> CNT_SHIFT) + (pp >> CNT_SHIFT));
        cdf[3 + ch][t] = (float)gfin[3 * NRBINS + ch * NBINS + t];
    }
    __syncthreads();
    // Hillis-Steele inclusive scan; partials are integers < 2^24 -> exact
    #pragma unroll
    for (int off = 1; off < NBINS; off <<= 1) {
        float add[6];
        #pragma unroll
        for (int j = 0; j < 6; ++j) add[j] = (t >= off) ? cdf[j][t - off] : 0.0f;
        __syncthreads();
        #pragma unroll
        for (int j = 0; j < 6; ++j) cdf[j][t] += add[j];
        __syncthreads();
    }
    if (t < 6) tot[t] = fmaxf(cdf[t][NBINS - 1], 1.0f);
    __syncthreads();
    #pragma unroll
    for (int j = 0; j < 6; ++j) cdf[j][t] = cdf[j][t] / tot[j];
    __syncthreads();

    double lsum = 0.0;
    #pragma unroll
    for (int ch = 0; ch < 3; ++ch) {
        const float d = cdf[ch][t];
        const float* ref = cdf[3 + ch];
        // searchsorted side='left': first idx with ref[idx] >= d
        int lo = 0, hi = NBINS;
        while (lo < hi) {
            int mid = (lo + hi) >> 1;
            if (ref[mid] < d) lo = mid + 1; else hi = mid;
        }
        int cand = min(max(lo, 1), NBINS - 1);
        int T = (ref[cand - 1] <= d && ref[cand] >= d) ? cand : t;
        if (t == 0) T = 0;
        if (t == NBINS - 1) T = NBINS - 1;

        // trunc-bin t stats: r=2t and r=2t+1
        const int b = t;
        const double c =
            (double)((pe[ch] >> CNT_SHIFT) + (po[ch] >> CNT_SHIFT));
        const double F =
            (double)((pe[ch] & FRAC_MASK) + (po[ch] & FRAC_MASK)) *
            (1.0 / 4194304.0);
        // pixels with trunc(v)=b: |v-T| = (b-T)+f if T<=b else (T-b)-f
        lsum += (T <= b) ? (c * (double)(b - T) + F)
                         : (c * (double)(T - b) - F);
    }
    // reduce doubles across 4 waves
    #pragma unroll
    for (int off = 32; off; off >>= 1) lsum += __shfl_down(lsum, off, 64);
    __shared__ double wsum[4];
    if ((t & 63) == 0) wsum[t >> 6] = lsum;
    __syncthreads();
    if (t == 0)
        out[0] = (float)((wsum[0] + wsum[1] + wsum[2] + wsum[3]) /
                         (double)(3 * NPIX));
}

extern "C" void kernel_launch(void* const* d_in, const int* in_sizes, int n_in,
                              void* d_out, int out_size, void* d_ws, size_t ws_size,
                              hipStream_t stream) {
    const float* in  = (const float*)d_in[0];
    const float* tar = (const float*)d_in[1];
    const float* ms  = (const float*)d_in[2];
    const float* mt  = (const float*)d_in[3];
    float* out = (float*)d_out;

    unsigned long long* part = (unsigned long long*)d_ws;
    unsigned long long* gfin = (unsigned long long*)((char*)d_ws + PART_BYTES);

    hipMemsetAsync(d_ws, 0, WS_ZERO_BYTES, stream);
    fused_hist<<<BLOCKS, THREADS, 0, stream>>>(in, tar, ms, mt, part);
    reduce_kernel<<<NWORDS / 256, 256, 0, stream>>>(part, gfin);
    table_loss<<<1, NBINS, 0, stream>>>(gfin, out);
}